// Round 7
// baseline (10296.005 us; speedup 1.0000x reference)
//
#include <hip/hip_runtime.h>

// ---------------------------------------------------------------------------
// OmniAnomaly forward, round 7: weight-stationary persistent mega-kernel,
// 512-thread WGs (8 waves -> 2 waves/SIMD) for latency hiding.
// WGs 0..127 = Qnet, WGs 128..255 = Pnet (pipelined via z-queue).
// GRU weight slice (110.8 KB) LDS-resident. Cross-WG activations: relaxed
// agent-scope atomics. Per-half flag barriers, fence-free (proven r5/r6).
// B=256, W=128, IN=128, H=1024, Z=128, D=1024, OUT=128, K=3 flows
// ---------------------------------------------------------------------------

typedef __bf16 bf16;
typedef __bf16 bf16x4 __attribute__((ext_vector_type(4)));
typedef __bf16 bf16x8 __attribute__((ext_vector_type(8)));
typedef float  f32x4  __attribute__((ext_vector_type(4)));
typedef unsigned long long u64;
typedef unsigned u32;

static constexpr int CB   = 256;
static constexpr int CW   = 128;
static constexpr int CIN  = 128;
static constexpr int CH   = 1024;
static constexpr int CZ   = 128;
static constexpr int CD   = 1024;
static constexpr int COUT = 128;

// LDS layout
static constexpr int ROWP       = 3 * CH + 3 * CIN + 8;     // 3464 elems/row
static constexpr int WS_BYTES   = 16 * ROWP * 2;            // 110848
static constexpr int REDN       = 8 * 16 * 17;              // per reduce buf (floats)
static constexpr int RED2_BYTES = 2 * REDN * 4;             // 17408
static constexpr int FLOW_BYTES = (2 * CZ + 2 * 2 * CZ) * 4; // zl + ps = 3072
static constexpr int SMEM_BYTES = WS_BYTES + RED2_BYTES + FLOW_BYTES; // 131328

#define DEV static __device__ __forceinline__

DEV float sigmoidf_(float x) { return 1.0f / (1.0f + expf(-x)); }
DEV float softplusf_(float x) { return x > 20.0f ? x : log1pf(expf(x)); }
DEV bf16x8 ldfrag(const bf16* p) { return *reinterpret_cast<const bf16x8*>(p); }

#define MFMA(a, b, c) __builtin_amdgcn_mfma_f32_16x16x32_bf16((a), (b), (c), 0, 0, 0)

// ---- relaxed agent-scope access helpers (proven r4-r6) ----
DEV u64 lda8(const void* p) {
    return __hip_atomic_load((const u64*)p, __ATOMIC_RELAXED, __HIP_MEMORY_SCOPE_AGENT);
}
DEV void sta8(void* p, u64 v) {
    __hip_atomic_store((u64*)p, v, __ATOMIC_RELAXED, __HIP_MEMORY_SCOPE_AGENT);
}
DEV u32 lda4(const void* p) {
    return __hip_atomic_load((const u32*)p, __ATOMIC_RELAXED, __HIP_MEMORY_SCOPE_AGENT);
}
DEV void sta4(void* p, u32 v) {
    __hip_atomic_store((u32*)p, v, __ATOMIC_RELAXED, __HIP_MEMORY_SCOPE_AGENT);
}
DEV bf16x8 ld_act16(const bf16* p) {
    union { u64 u[2]; bf16x8 v; } r;
    r.u[0] = lda8(p);
    r.u[1] = lda8((const char*)p + 8);
    return r.v;
}
DEV u32 pk2(float a, float b) {
    union { bf16 h[2]; u32 u; } r;
    r.h[0] = (bf16)a; r.h[1] = (bf16)b;
    return r.u;
}

struct Prm {
    const float *eps_q, *eps_p;
    const float *bih_q, *bhh_q, *bd_q, *bmu_q, *bsig_q;
    const float *Wp, *bp, *up, *Wlg, *blg;
    const float *bih_p, *bhh_p, *bd_p, *bmu_p, *bsig_p;
    const bf16 *x_b, *Wih_qb, *Whh_qb, *Wd_qb, *Wmu_qb, *Wsg_qb;
    const bf16 *Wih_pb, *Whh_pb, *Wd_pb, *Wmu_pb, *Wsg_pb;
    float *e_f0, *e_f1; bf16 *e_b0, *e_b1;
    float *d_f0, *d_f1; bf16 *d_b0, *d_b1;
    float *ztmp_f;
    bf16 *dvec_b, *ddvec_b;
    bf16 *zflow;    // [CW+1][CB][CZ], slot 0 zeroed
    bf16 *ztlg;     // [CW][CB][CZ]
    u32 *barQ, *barP, *zbar;
    float *out_o, *out_mu, *out_lv;
};

// Per-half fence-free barrier over 128 WGs (flag array, vmcnt drain).
DEV void gbar_h(u32* bar, int wgl, u32 k)
{
    asm volatile("s_waitcnt vmcnt(0)" ::: "memory");
    __syncthreads();
    if (threadIdx.x == 0)
        __hip_atomic_store(&bar[wgl], k, __ATOMIC_RELAXED, __HIP_MEMORY_SCOPE_AGENT);
    if (threadIdx.x < 128) {
        while (__hip_atomic_load(&bar[threadIdx.x], __ATOMIC_RELAXED,
                                 __HIP_MEMORY_SCOPE_AGENT) < k)
            __builtin_amdgcn_s_sleep(4);
    }
    __syncthreads();
}

// ---------------------------------------------------------------------------
__global__ void k_cvt(const float* __restrict__ src, bf16* __restrict__ dst, int n)
{
    int i = (blockIdx.x * blockDim.x + threadIdx.x) * 4;
    if (i < n) {
        float4 v = *reinterpret_cast<const float4*>(src + i);
        bf16x4 o;
        o[0] = (bf16)v.x; o[1] = (bf16)v.y; o[2] = (bf16)v.z; o[3] = (bf16)v.w;
        *reinterpret_cast<bf16x4*>(dst + i) = o;
    }
}

// ---------------------------------------------------------------------------
// GRU phase, 8 waves, 1 frag/wave: WG (ms=wgl>>6, ns=wgl&63) computes rows
// [ms*128,+128) x cols [ns*16,+16); wave w owns rows ms*128+w*16..+16, full K.
// ---------------------------------------------------------------------------
DEV void phase_gru2(int wgl, int lane, int wave, int lr, int lkE, const bf16* WS,
                    const bf16* __restrict__ Xin, long xstride, int xagent,
                    const bf16* __restrict__ Ebin, const float* __restrict__ Efin,
                    const float* __restrict__ bih, const float* __restrict__ bhh,
                    float* __restrict__ Efo, bf16* __restrict__ Ebo)
{
    const int ns = wgl & 63, ms = wgl >> 6;
    const int n0 = ns * 16;
    const int rA0 = ms * 128 + wave * 16 + lr;
    const bf16* wsrow = WS + (long)lr * ROWP;

    f32x4 acc[4] = {};   // groups: 0=r, 1=z, 2=n_input, 3=n_hidden

    // input part K = 128
#pragma unroll
    for (int k = 0; k < CIN; k += 32) {
        bf16x8 a0 = xagent ? ld_act16(Xin + (long)rA0 * xstride + k + lkE)
                           : ldfrag(Xin + (long)rA0 * xstride + k + lkE);
#pragma unroll
        for (int g = 0; g < 3; ++g) {
            bf16x8 b = *reinterpret_cast<const bf16x8*>(wsrow + 3 * CH + g * CIN + k + lkE);
            const int grp = (g == 2) ? 2 : g;
            acc[grp] = MFMA(a0, b, acc[grp]);
        }
    }
    // hidden part K = 1024
#pragma unroll 8
    for (int k = 0; k < CH; k += 32) {
        bf16x8 a0 = ld_act16(Ebin + (long)rA0 * CH + k + lkE);
#pragma unroll
        for (int g = 0; g < 3; ++g) {
            bf16x8 b = *reinterpret_cast<const bf16x8*>(wsrow + g * CH + k + lkE);
            const int grp = (g == 2) ? 3 : g;
            acc[grp] = MFMA(a0, b, acc[grp]);
        }
    }

    // epilogue: C frag mapping row=(lane>>4)*4+i, col=lane&15 (HW-verified)
    const int col = n0 + lr;
    const float b0r = bih[col] + bhh[col];
    const float b0z = bih[CH + col] + bhh[CH + col];
    const float bin = bih[2 * CH + col];
    const float bhn = bhh[2 * CH + col];
    const int rbase = ms * 128 + wave * 16 + (lane >> 4) * 4;
#pragma unroll
    for (int i = 0; i < 4; ++i) {
        const int row = rbase + i;
        float gr = acc[0][i] + b0r;
        float gz = acc[1][i] + b0z;
        float gi = acc[2][i] + bin;
        float gh = acc[3][i] + bhn;
        float r = sigmoidf_(gr);
        float u = sigmoidf_(gz);
        float n = tanhf(gi + r * gh);
        float en = (1.0f - u) * n + u * Efin[(long)row * CH + col];
        Efo[(long)row * CH + col] = en;
        float vB = __shfl_xor(en, 1);
        if (!(lane & 1))
            sta4(Ebo + (long)row * CH + col, pk2(en, vB));
    }
}

// ---------------------------------------------------------------------------
// Linear phase (weights from global/L2), 8 waves, 1 frag/wave.
// ---------------------------------------------------------------------------
DEV void phase_lin2(int wgl, int lane, int wave, int lr, int lkE,
                    const bf16* __restrict__ A1, long a1s,
                    const bf16* __restrict__ A2,
                    const bf16* __restrict__ W, int ldw,
                    const float* __restrict__ bias, bf16* __restrict__ Out)
{
    const int ns = wgl & 63, ms = wgl >> 6;
    const int n0 = ns * 16;
    const int rA0 = ms * 128 + wave * 16 + lr;
    const bf16* wrow = W + (long)(n0 + lr) * ldw;

    f32x4 acc = {};
    int koff = 0;
    if (A1) {
#pragma unroll
        for (int k = 0; k < CZ; k += 32) {
            bf16x8 a0 = ld_act16(A1 + (long)rA0 * a1s + k + lkE);
            bf16x8 b  = ldfrag(wrow + k + lkE);
            acc = MFMA(a0, b, acc);
        }
        koff = CZ;
    }
#pragma unroll 8
    for (int k = 0; k < CH; k += 32) {
        bf16x8 a0 = ld_act16(A2 + (long)rA0 * CH + k + lkE);
        bf16x8 b  = ldfrag(wrow + koff + k + lkE);
        acc = MFMA(a0, b, acc);
    }

    const int col = n0 + lr;
    const float bb = bias[col];
    const int rbase = ms * 128 + wave * 16 + (lane >> 4) * 4;
#pragma unroll
    for (int i = 0; i < 4; ++i) {
        float v = acc[i] + bb;
        float vB = __shfl_xor(v, 1);
        if (!(lane & 1))
            sta4(Out + (long)(rbase + i) * CD + col, pk2(v, vB));
    }
}

// ---------------------------------------------------------------------------
// Two-head tail: 16x16 tile per WG, 8-wave K-split (chunk 128), single-round
// double-buffer LDS reduce. MODE 0: qnet (mu,lv,z); MODE 1: pnet out.
// ---------------------------------------------------------------------------
template <int MODE>
DEV void phase_tail2(const Prm& p, int t, int wgl, int tid, int lane, int wave,
                     int lr, int lkE, float* Ra, float* Rs,
                     const bf16* __restrict__ A,
                     const bf16* __restrict__ Wa, const bf16* __restrict__ Wb,
                     const float* __restrict__ ba, const float* __restrict__ bb)
{
    const int mb = (wgl >> 3) << 4;   // 0..240
    const int nb = (wgl & 7) << 4;    // 0..112
    f32x4 am = {}, as = {};
    const int k0 = wave * 128;
#pragma unroll
    for (int kk = 0; kk < 128; kk += 32) {
        const int k = k0 + kk;
        bf16x8 a  = ld_act16(A + (long)(mb + lr) * CD + k + lkE);
        bf16x8 bm = ldfrag(Wa + (long)(nb + lr) * CD + k + lkE);
        bf16x8 bs = ldfrag(Wb + (long)(nb + lr) * CD + k + lkE);
        am = MFMA(a, bm, am);
        as = MFMA(a, bs, as);
    }
    __syncthreads();
#pragma unroll
    for (int i = 0; i < 4; ++i) {
        Ra[(wave * 16 + (lane >> 4) * 4 + i) * 17 + lr] = am[i];
        Rs[(wave * 16 + (lane >> 4) * 4 + i) * 17 + lr] = as[i];
    }
    __syncthreads();
    if (tid < 256) {
        const int trow = tid >> 4, tcol = tid & 15;
        float vm = 0.f, vs = 0.f;
#pragma unroll
        for (int w = 0; w < 8; ++w) {
            vm += Ra[(w * 16 + trow) * 17 + tcol];
            vs += Rs[(w * 16 + trow) * 17 + tcol];
        }
        const int row = mb + trow, col = nb + tcol;
        if constexpr (MODE == 0) {
            float mu = vm + ba[col];
            float lv = softplusf_(vs + bb[col]);
            float e  = p.eps_q[(long)row * CW * CZ + (long)t * CZ + col];
            float z  = mu + expf(0.5f * lv) * e;
            p.out_mu[(long)row * CW * CZ + (long)t * CZ + col] = mu;
            p.out_lv[(long)row * CW * CZ + (long)t * CZ + col] = lv;
            sta4(p.ztmp_f + (long)row * CZ + col, __float_as_uint(z));
        } else {
            float m  = vm + ba[col];
            float sg = softplusf_(vs + bb[col]);
            float e  = p.eps_p[(long)row * CW * COUT + (long)t * COUT + col];
            p.out_o[(long)row * CW * COUT + (long)t * COUT + col] = m + sg * e;
        }
    }
}

// ---------------------------------------------------------------------------
// Planar flows + LGSSM linear (Q half): 2 batch rows/WG, 512 threads
// (rg = tid>>8 selects row; within rg: c = col, half = dot-half).
// ---------------------------------------------------------------------------
DEV void phase_flows2(const Prm& p, int wgl, int tid, int t, float* zl, float* ps)
{
    const int rg = tid >> 8;            // 0..1
    const int sub = tid & 255;
    const int c = sub & 127, half = sub >> 7;
    const int row = wgl * 2 + rg;
    float* zrow = zl + rg * CZ;
    float* pall = ps + rg * 2 * CZ;     // [half][CZ]

    if (half == 0)
        zrow[c] = __uint_as_float(lda4(p.ztmp_f + (long)row * CZ + c));
    __syncthreads();

#pragma unroll 1
    for (int kf = 0; kf < 3; ++kf) {
        const float* wr = p.Wp + ((long)kf * CZ + c) * CZ + half * 64;
        const float* zh = zrow + half * 64;
        float s = 0.f;
#pragma unroll
        for (int j = 0; j < 64; j += 4) {
            float4 w  = *reinterpret_cast<const float4*>(wr + j);
            s += zh[j] * w.x + zh[j + 1] * w.y + zh[j + 2] * w.z + zh[j + 3] * w.w;
        }
        pall[half * CZ + c] = s;
        __syncthreads();
        if (half == 0) {
            float sf = pall[c] + pall[CZ + c] + p.bp[kf * CZ + c];
            zrow[c] += p.up[kf] * tanhf(sf);
        }
        __syncthreads();
    }
    {
        const float* wr = p.Wlg + (long)c * CZ + half * 64;
        const float* zh = zrow + half * 64;
        float s = 0.f;
#pragma unroll
        for (int j = 0; j < 64; j += 4) {
            float4 w  = *reinterpret_cast<const float4*>(wr + j);
            s += zh[j] * w.x + zh[j + 1] * w.y + zh[j + 2] * w.z + zh[j + 3] * w.w;
        }
        pall[half * CZ + c] = s;
        __syncthreads();
        if (half == 0) {
            float zt = pall[c] + pall[CZ + c] + p.blg[c];
            float ztB = __shfl_xor(zt, 1);
            if (!(c & 1)) {
                sta4(p.ztlg  + ((size_t)t * CB + row) * CZ + c, pk2(zt, ztB));
                sta4(p.zflow + ((size_t)(t + 1) * CB + row) * CZ + c,
                     pk2(zrow[c], zrow[c + 1]));
            }
        }
    }
}

// ---------------------------------------------------------------------------
// Mega kernel: 512 threads, 8 waves.
// ---------------------------------------------------------------------------
__launch_bounds__(512)
__global__ void mega(Prm p)
{
    extern __shared__ char smem[];
    bf16*  WS  = (bf16*)smem;
    float* Ra  = (float*)(smem + WS_BYTES);
    float* Rs  = Ra + REDN;
    float* ZLp = (float*)(smem + WS_BYTES + RED2_BYTES);
    float* PSp = ZLp + 2 * CZ;

    const int wg = blockIdx.x, tid = threadIdx.x;
    const int lane = tid & 63, wave = tid >> 6;
    const int lr = lane & 15, lkE = (lane >> 4) * 8;
    const bool isQ = wg < 128;
    const int wgl = isQ ? wg : wg - 128;

    // ---- preload GRU weight slice into LDS (once) ----
    {
        const bf16* Whh = isQ ? p.Whh_qb : p.Whh_pb;
        const bf16* Wih = isQ ? p.Wih_qb : p.Wih_pb;
        const int ns = wgl & 63;
        const int kk = tid * 8;
        for (int r = 0; r < 16; ++r) {
#pragma unroll
            for (int g = 0; g < 3; ++g) {
                if (kk < CH)
                    *reinterpret_cast<bf16x8*>(&WS[(long)r * ROWP + g * CH + kk]) =
                        ldfrag(Whh + ((long)g * CH + ns * 16 + r) * CH + kk);
                if (kk < CIN)
                    *reinterpret_cast<bf16x8*>(&WS[(long)r * ROWP + 3 * CH + g * CIN + kk]) =
                        ldfrag(Wih + ((long)g * CH + ns * 16 + r) * CIN + kk);
            }
        }
        __syncthreads();
    }

    if (isQ) {
        u32 bk = 0;
#pragma unroll 1
        for (int t = 0; t < CW; ++t) {
            const int bi = t & 1;
            const bf16*  eb_i = bi ? p.e_b1 : p.e_b0;
            const float* ef_i = bi ? p.e_f1 : p.e_f0;
            bf16*  eb_o = bi ? p.e_b0 : p.e_b1;
            float* ef_o = bi ? p.e_f0 : p.e_f1;

            phase_gru2(wgl, lane, wave, lr, lkE, WS,
                       p.x_b + (long)t * CIN, (long)CW * CIN, 0,
                       eb_i, ef_i, p.bih_q, p.bhh_q, ef_o, eb_o);
            gbar_h(p.barQ, wgl, ++bk);
            phase_lin2(wgl, lane, wave, lr, lkE,
                       p.zflow + (size_t)t * CB * CZ, CZ,
                       eb_o, p.Wd_qb, CZ + CH, p.bd_q, p.dvec_b);
            gbar_h(p.barQ, wgl, ++bk);
            phase_tail2<0>(p, t, wgl, tid, lane, wave, lr, lkE, Ra, Rs,
                           p.dvec_b, p.Wmu_qb, p.Wsg_qb, p.bmu_q, p.bsig_q);
            gbar_h(p.barQ, wgl, ++bk);
            phase_flows2(p, wgl, tid, t, ZLp, PSp);
            // publish z availability
            asm volatile("s_waitcnt vmcnt(0)" ::: "memory");
            __syncthreads();
            if (tid == 0)
                __hip_atomic_store(&p.zbar[wgl], (u32)(t + 1),
                                   __ATOMIC_RELAXED, __HIP_MEMORY_SCOPE_AGENT);
            __syncthreads();
        }
    } else {
        u32 bk = 0;
#pragma unroll 1
        for (int t = 0; t < CW; ++t) {
            if (tid < 128) {
                while (__hip_atomic_load(&p.zbar[tid], __ATOMIC_RELAXED,
                                         __HIP_MEMORY_SCOPE_AGENT) < (u32)(t + 1))
                    __builtin_amdgcn_s_sleep(8);
            }
            __syncthreads();

            const int bi = t & 1;
            const bf16*  db_i = bi ? p.d_b1 : p.d_b0;
            const float* df_i = bi ? p.d_f1 : p.d_f0;
            bf16*  db_o = bi ? p.d_b0 : p.d_b1;
            float* df_o = bi ? p.d_f0 : p.d_f1;

            phase_gru2(wgl, lane, wave, lr, lkE, WS,
                       p.ztlg + (size_t)t * CB * CZ, CZ, 1,
                       db_i, df_i, p.bih_p, p.bhh_p, df_o, db_o);
            gbar_h(p.barP, wgl, ++bk);
            phase_lin2(wgl, lane, wave, lr, lkE,
                       nullptr, 0, db_o, p.Wd_pb, CH, p.bd_p, p.ddvec_b);
            gbar_h(p.barP, wgl, ++bk);
            phase_tail2<1>(p, t, wgl, tid, lane, wave, lr, lkE, Ra, Rs,
                           p.ddvec_b, p.Wmu_pb, p.Wsg_pb, p.bmu_p, p.bsig_p);
            // ddvec reuse protected by next barP (after GRU t+1)
        }
    }
}

// ---------------------------------------------------------------------------
// Host driver
// ---------------------------------------------------------------------------
extern "C" void kernel_launch(void* const* d_in, const int* in_sizes, int n_in,
                              void* d_out, int out_size, void* d_ws, size_t ws_size,
                              hipStream_t stream)
{
    Prm p;
    const float* x      = (const float*)d_in[0];
    p.eps_q  = (const float*)d_in[1];
    p.eps_p  = (const float*)d_in[2];
    const float* Wih_q  = (const float*)d_in[3];
    const float* Whh_q  = (const float*)d_in[4];
    p.bih_q  = (const float*)d_in[5];
    p.bhh_q  = (const float*)d_in[6];
    const float* Wd_q   = (const float*)d_in[7];
    p.bd_q   = (const float*)d_in[8];
    const float* Wmu_q  = (const float*)d_in[9];
    p.bmu_q  = (const float*)d_in[10];
    const float* Wsig_q = (const float*)d_in[11];
    p.bsig_q = (const float*)d_in[12];
    p.Wp     = (const float*)d_in[13];
    p.bp     = (const float*)d_in[14];
    p.up     = (const float*)d_in[15];
    p.Wlg    = (const float*)d_in[16];
    p.blg    = (const float*)d_in[17];
    const float* Wih_p  = (const float*)d_in[18];
    const float* Whh_p  = (const float*)d_in[19];
    p.bih_p  = (const float*)d_in[20];
    p.bhh_p  = (const float*)d_in[21];
    const float* Wd_p   = (const float*)d_in[22];
    p.bd_p   = (const float*)d_in[23];
    const float* Wmu_p  = (const float*)d_in[24];
    p.bmu_p  = (const float*)d_in[25];
    const float* Wsig_p = (const float*)d_in[26];
    p.bsig_p = (const float*)d_in[27];

    p.out_o  = (float*)d_out;
    p.out_mu = p.out_o + (size_t)CB * CW * COUT;
    p.out_lv = p.out_mu + (size_t)CB * CW * CZ;

    char* wp_ = (char*)d_ws;
    auto carve = [&](size_t bytes) -> void* {
        void* q = (void*)wp_;
        wp_ += (bytes + 255) & ~(size_t)255;
        return q;
    };
    p.e_f0 = (float*)carve((size_t)CB * CH * 4);
    p.e_f1 = (float*)carve((size_t)CB * CH * 4);
    p.e_b0 = (bf16*)carve((size_t)CB * CH * 2);
    p.e_b1 = (bf16*)carve((size_t)CB * CH * 2);
    p.d_f0 = (float*)carve((size_t)CB * CH * 4);
    p.d_f1 = (float*)carve((size_t)CB * CH * 4);
    p.d_b0 = (bf16*)carve((size_t)CB * CH * 2);
    p.d_b1 = (bf16*)carve((size_t)CB * CH * 2);
    p.ztmp_f  = (float*)carve((size_t)CB * CZ * 4);
    p.dvec_b  = (bf16*)carve((size_t)CB * CD * 2);
    p.ddvec_b = (bf16*)carve((size_t)CB * CD * 2);
    p.zflow   = (bf16*)carve((size_t)(CW + 1) * CB * CZ * 2);
    p.ztlg    = (bf16*)carve((size_t)CW * CB * CZ * 2);
    p.barQ    = (u32*)carve(512);
    p.barP    = (u32*)carve(512);
    p.zbar    = (u32*)carve(512);
    bf16* x_b    = (bf16*)carve((size_t)CB * CW * CIN * 2);
    bf16* Wih_qb = (bf16*)carve((size_t)3 * CH * CIN * 2);
    bf16* Whh_qb = (bf16*)carve((size_t)3 * CH * CH * 2);
    bf16* Wd_qb  = (bf16*)carve((size_t)CD * (CZ + CH) * 2);
    bf16* Wmu_qb = (bf16*)carve((size_t)CZ * CD * 2);
    bf16* Wsg_qb = (bf16*)carve((size_t)CZ * CD * 2);
    bf16* Wih_pb = (bf16*)carve((size_t)3 * CH * CZ * 2);
    bf16* Whh_pb = (bf16*)carve((size_t)3 * CH * CH * 2);
    bf16* Wd_pb  = (bf16*)carve((size_t)CD * CH * 2);
    bf16* Wmu_pb = (bf16*)carve((size_t)COUT * CD * 2);
    bf16* Wsg_pb = (bf16*)carve((size_t)COUT * CD * 2);
    p.x_b = x_b;       p.Wih_qb = Wih_qb; p.Whh_qb = Whh_qb;
    p.Wd_qb = Wd_qb;   p.Wmu_qb = Wmu_qb; p.Wsg_qb = Wsg_qb;
    p.Wih_pb = Wih_pb; p.Whh_pb = Whh_pb; p.Wd_pb = Wd_pb;
    p.Wmu_pb = Wmu_pb; p.Wsg_pb = Wsg_pb;

    hipMemsetAsync(p.e_f0, 0, (size_t)CB * CH * 4, stream);
    hipMemsetAsync(p.e_b0, 0, (size_t)CB * CH * 2, stream);
    hipMemsetAsync(p.d_f0, 0, (size_t)CB * CH * 4, stream);
    hipMemsetAsync(p.d_b0, 0, (size_t)CB * CH * 2, stream);
    hipMemsetAsync(p.zflow, 0, (size_t)CB * CZ * 2, stream);   // slot 0 = zeros
    hipMemsetAsync(p.barQ, 0, 512, stream);
    hipMemsetAsync(p.barP, 0, 512, stream);
    hipMemsetAsync(p.zbar, 0, 512, stream);

    auto cvt = [&](const float* s, bf16* d, size_t n) {
        k_cvt<<<dim3((unsigned)((n / 4 + 255) / 256)), dim3(256), 0, stream>>>(s, d, (int)n);
    };
    cvt(x,      x_b,    (size_t)CB * CW * CIN);
    cvt(Wih_q,  Wih_qb, (size_t)3 * CH * CIN);
    cvt(Whh_q,  Whh_qb, (size_t)3 * CH * CH);
    cvt(Wd_q,   Wd_qb,  (size_t)CD * (CZ + CH));
    cvt(Wmu_q,  Wmu_qb, (size_t)CZ * CD);
    cvt(Wsig_q, Wsg_qb, (size_t)CZ * CD);
    cvt(Wih_p,  Wih_pb, (size_t)3 * CH * CZ);
    cvt(Whh_p,  Whh_pb, (size_t)3 * CH * CH);
    cvt(Wd_p,   Wd_pb,  (size_t)CD * CH);
    cvt(Wmu_p,  Wmu_pb, (size_t)COUT * CD);
    cvt(Wsig_p, Wsg_pb, (size_t)COUT * CD);

    static bool attr_set = false;
    if (!attr_set) {
        hipFuncSetAttribute((const void*)mega,
                            hipFuncAttributeMaxDynamicSharedMemorySize, SMEM_BYTES);
        attr_set = true;
    }
    mega<<<dim3(256), dim3(512), SMEM_BYTES, stream>>>(p);
}

// Round 8
// 9719.785 us; speedup vs baseline: 1.0593x; 1.0593x over previous
//
#include <hip/hip_runtime.h>

// ---------------------------------------------------------------------------
// OmniAnomaly forward, round 8: M-major retile, LDS-staged activations,
// L2-stationary weights.
// WG = 16 batch rows (mslab=wgl>>3) x 128 cols (nsl=wgl&7). Activation slab
// (16 x K) staged once per phase into LDS via agent-scope loads (8x less
// fabric traffic than r7's N-major tiling); weights are read-only -> plain
// cached loads, one 128-col slice per XCD -> L2-resident across all steps.
// WGs 0..127 = Qnet, 128..255 = Pnet (pipelined via z-queue). Barrier
// structure identical to r7 (proven).
// B=256, W=128, IN=128, H=1024, Z=128, D=1024, OUT=128, K=3 flows
// ---------------------------------------------------------------------------

typedef __bf16 bf16;
typedef __bf16 bf16x4 __attribute__((ext_vector_type(4)));
typedef __bf16 bf16x8 __attribute__((ext_vector_type(8)));
typedef float  f32x4  __attribute__((ext_vector_type(4)));
typedef unsigned long long u64;
typedef unsigned u32;

static constexpr int CB   = 256;
static constexpr int CW   = 128;
static constexpr int CIN  = 128;
static constexpr int CH   = 1024;
static constexpr int CZ   = 128;
static constexpr int CD   = 1024;
static constexpr int COUT = 128;

// LDS layout
static constexpr int APITCH     = 1160;                    // 1152 + 8 pad (2-way banks)
static constexpr int ABUF_BYTES = 16 * APITCH * 2;         // 37120
static constexpr int REDN       = 8 * 16 * 17;             // floats per reduce buf
static constexpr int RED2_BYTES = 2 * REDN * 4;            // 17408
static constexpr int FLOW_BYTES = (2 * CZ + 2 * 2 * CZ) * 4; // 3072
static constexpr int SMEM_BYTES = ABUF_BYTES + RED2_BYTES + FLOW_BYTES; // 57600

#define DEV static __device__ __forceinline__

DEV float sigmoidf_(float x) { return 1.0f / (1.0f + expf(-x)); }
DEV float softplusf_(float x) { return x > 20.0f ? x : log1pf(expf(x)); }
DEV bf16x8 ldfrag(const bf16* p) { return *reinterpret_cast<const bf16x8*>(p); }

#define MFMA(a, b, c) __builtin_amdgcn_mfma_f32_16x16x32_bf16((a), (b), (c), 0, 0, 0)

// ---- relaxed agent-scope access helpers (proven r4-r7) ----
DEV u64 lda8(const void* p) {
    return __hip_atomic_load((const u64*)p, __ATOMIC_RELAXED, __HIP_MEMORY_SCOPE_AGENT);
}
DEV u32 lda4(const void* p) {
    return __hip_atomic_load((const u32*)p, __ATOMIC_RELAXED, __HIP_MEMORY_SCOPE_AGENT);
}
DEV void sta4(void* p, u32 v) {
    __hip_atomic_store((u32*)p, v, __ATOMIC_RELAXED, __HIP_MEMORY_SCOPE_AGENT);
}
DEV bf16x8 ld_act16(const bf16* p) {
    union { u64 u[2]; bf16x8 v; } r;
    r.u[0] = lda8(p);
    r.u[1] = lda8((const char*)p + 8);
    return r.v;
}
DEV u32 pk2(float a, float b) {
    union { bf16 h[2]; u32 u; } r;
    r.h[0] = (bf16)a; r.h[1] = (bf16)b;
    return r.u;
}

struct Prm {
    const float *eps_q, *eps_p;
    const float *bih_q, *bhh_q, *bd_q, *bmu_q, *bsig_q;
    const float *Wp, *bp, *up, *Wlg, *blg;
    const float *bih_p, *bhh_p, *bd_p, *bmu_p, *bsig_p;
    const bf16 *x_b, *Wih_qb, *Whh_qb, *Wd_qb, *Wmu_qb, *Wsg_qb;
    const bf16 *Wih_pb, *Whh_pb, *Wd_pb, *Wmu_pb, *Wsg_pb;
    float *e_f0, *e_f1; bf16 *e_b0, *e_b1;
    float *d_f0, *d_f1; bf16 *d_b0, *d_b1;
    float *ztmp_f;
    bf16 *dvec_b, *ddvec_b;
    bf16 *zflow;    // [CW+1][CB][CZ], slot 0 zeroed
    bf16 *ztlg;     // [CW][CB][CZ]
    u32 *barQ, *barP, *zbar;
    float *out_o, *out_mu, *out_lv;
};

// Per-half fence-free barrier over 128 WGs (flag array, vmcnt drain).
DEV void gbar_h(u32* bar, int wgl, u32 k)
{
    asm volatile("s_waitcnt vmcnt(0)" ::: "memory");
    __syncthreads();
    if (threadIdx.x == 0)
        __hip_atomic_store(&bar[wgl], k, __ATOMIC_RELAXED, __HIP_MEMORY_SCOPE_AGENT);
    if (threadIdx.x < 128) {
        while (__hip_atomic_load(&bar[threadIdx.x], __ATOMIC_RELAXED,
                                 __HIP_MEMORY_SCOPE_AGENT) < k)
            __builtin_amdgcn_s_sleep(1);
    }
    __syncthreads();
}

// ---------------------------------------------------------------------------
__global__ void k_cvt(const float* __restrict__ src, bf16* __restrict__ dst, int n)
{
    int i = (blockIdx.x * blockDim.x + threadIdx.x) * 4;
    if (i < n) {
        float4 v = *reinterpret_cast<const float4*>(src + i);
        bf16x4 o;
        o[0] = (bf16)v.x; o[1] = (bf16)v.y; o[2] = (bf16)v.z; o[3] = (bf16)v.w;
        *reinterpret_cast<bf16x4*>(dst + i) = o;
    }
}

// ---------------------------------------------------------------------------
// Stage activation slab rows [r0, r0+16) x [head(K1) | body(K2)] into abuf.
// ---------------------------------------------------------------------------
DEV void stage_act(bf16* abuf, int tid, int r0,
                   const bf16* __restrict__ head, long hs, int K1, int hagent,
                   const bf16* __restrict__ body, long bs)
{
    const int CHN = (K1 + CH) >> 3;    // 16B chunks per row (body K always CH)
    const int TOT = 16 * CHN;
    for (int idx = tid; idx < TOT; idx += 512) {
        const int row = idx / CHN;
        const int k = (idx - row * CHN) * 8;
        bf16x8 v;
        if (k < K1) {
            const bf16* s = head + (long)(r0 + row) * hs + k;
            v = hagent ? ld_act16(s) : ldfrag(s);
        } else {
            v = ld_act16(body + (long)(r0 + row) * bs + (k - K1));
        }
        *reinterpret_cast<bf16x8*>(abuf + (long)row * APITCH + k) = v;
    }
    __syncthreads();
}

// ---------------------------------------------------------------------------
// GRU compute from staged LDS acts. WG: rows r0..+16, cols nsl*128..+128;
// wave owns 16 cols. Weights: plain cached loads (read-only, L2-resident).
// ---------------------------------------------------------------------------
DEV void gru_compute(const Prm& p, const bf16* abuf, int r0, int n0,
                     int lane, int wave,
                     const bf16* __restrict__ Wih, const bf16* __restrict__ Whh,
                     const float* __restrict__ bih, const float* __restrict__ bhh,
                     const float* __restrict__ Efin,
                     float* __restrict__ Efo, bf16* __restrict__ Ebo)
{
    const int lr = lane & 15, lkE = (lane >> 4) * 8;
    const int c = n0 + wave * 16 + lr;          // weight row / output col
    const bf16* arow = abuf + (long)lr * APITCH;

    f32x4 acc[4] = {};   // 0=r, 1=z, 2=n_input, 3=n_hidden
#pragma unroll 4
    for (int k = 0; k < CIN; k += 32) {
        bf16x8 a = *reinterpret_cast<const bf16x8*>(arow + k + lkE);
#pragma unroll
        for (int g = 0; g < 3; ++g) {
            bf16x8 b = ldfrag(Wih + ((long)g * CH + c) * CIN + k + lkE);
            const int grp = (g == 2) ? 2 : g;
            acc[grp] = MFMA(a, b, acc[grp]);
        }
    }
#pragma unroll 4
    for (int k = 0; k < CH; k += 32) {
        bf16x8 a = *reinterpret_cast<const bf16x8*>(arow + CIN + k + lkE);
#pragma unroll
        for (int g = 0; g < 3; ++g) {
            bf16x8 b = ldfrag(Whh + ((long)g * CH + c) * CH + k + lkE);
            const int grp = (g == 2) ? 3 : g;
            acc[grp] = MFMA(a, b, acc[grp]);
        }
    }

    const float b0r = bih[c] + bhh[c];
    const float b0z = bih[CH + c] + bhh[CH + c];
    const float bin = bih[2 * CH + c];
    const float bhn = bhh[2 * CH + c];
    const int rbase = r0 + (lane >> 4) * 4;
#pragma unroll
    for (int i = 0; i < 4; ++i) {
        const int row = rbase + i;
        float gr = acc[0][i] + b0r;
        float gz = acc[1][i] + b0z;
        float gi = acc[2][i] + bin;
        float gh = acc[3][i] + bhn;
        float r = sigmoidf_(gr);
        float u = sigmoidf_(gz);
        float n = tanhf(gi + r * gh);
        float en = (1.0f - u) * n + u * Efin[(long)row * CH + c];
        Efo[(long)row * CH + c] = en;
        float vB = __shfl_xor(en, 1);
        if (!(lane & 1))
            sta4(Ebo + (long)row * CH + c, pk2(en, vB));
    }
}

// ---------------------------------------------------------------------------
// Linear compute from staged LDS acts: Out[r0..+16][n0+wave*16..+16].
// ---------------------------------------------------------------------------
DEV void lin_compute(const bf16* abuf, int r0, int n0, int lane, int wave, int Ktot,
                     const bf16* __restrict__ W,
                     const float* __restrict__ bias, bf16* __restrict__ Out)
{
    const int lr = lane & 15, lkE = (lane >> 4) * 8;
    const int c = n0 + wave * 16 + lr;
    const bf16* arow = abuf + (long)lr * APITCH;
    const bf16* wrow = W + (long)c * Ktot;

    f32x4 acc = {};
#pragma unroll 4
    for (int k = 0; k < CH; k += 32) {          // body always CH; head folded below
        bf16x8 a = *reinterpret_cast<const bf16x8*>(arow + (Ktot - CH) + k + lkE);
        bf16x8 b = ldfrag(wrow + (Ktot - CH) + k + lkE);
        acc = MFMA(a, b, acc);
    }
    if (Ktot > CH) {
#pragma unroll 4
        for (int k = 0; k < CZ; k += 32) {
            bf16x8 a = *reinterpret_cast<const bf16x8*>(arow + k + lkE);
            bf16x8 b = ldfrag(wrow + k + lkE);
            acc = MFMA(a, b, acc);
        }
    }

    const float bb = bias[c];
    const int rbase = r0 + (lane >> 4) * 4;
#pragma unroll
    for (int i = 0; i < 4; ++i) {
        float v = acc[i] + bb;
        float vB = __shfl_xor(v, 1);
        if (!(lane & 1))
            sta4(Out + (long)(rbase + i) * CD + c, pk2(v, vB));
    }
}

// ---------------------------------------------------------------------------
// Two-head tail: r7 structure. 16x16 tile per WG, 8-wave K-split, LDS reduce.
// ---------------------------------------------------------------------------
template <int MODE>
DEV void phase_tail2(const Prm& p, int t, int wgl, int tid, int lane, int wave,
                     float* Ra, float* Rs, const bf16* __restrict__ A,
                     const bf16* __restrict__ Wa, const bf16* __restrict__ Wb,
                     const float* __restrict__ ba, const float* __restrict__ bb)
{
    const int lr = lane & 15, lkE = (lane >> 4) * 8;
    const int mb = (wgl >> 3) << 4;   // 0..240
    const int nb = (wgl & 7) << 4;    // 0..112 (XCD-aligned slice)
    f32x4 am = {}, as = {};
    const int k0 = wave * 128;
#pragma unroll
    for (int kk = 0; kk < 128; kk += 32) {
        const int k = k0 + kk;
        bf16x8 a  = ld_act16(A + (long)(mb + lr) * CD + k + lkE);
        bf16x8 bm = ldfrag(Wa + (long)(nb + lr) * CD + k + lkE);
        bf16x8 bs = ldfrag(Wb + (long)(nb + lr) * CD + k + lkE);
        am = MFMA(a, bm, am);
        as = MFMA(a, bs, as);
    }
    __syncthreads();
#pragma unroll
    for (int i = 0; i < 4; ++i) {
        Ra[(wave * 16 + (lane >> 4) * 4 + i) * 17 + lr] = am[i];
        Rs[(wave * 16 + (lane >> 4) * 4 + i) * 17 + lr] = as[i];
    }
    __syncthreads();
    if (tid < 256) {
        const int trow = tid >> 4, tcol = tid & 15;
        float vm = 0.f, vs = 0.f;
#pragma unroll
        for (int w = 0; w < 8; ++w) {
            vm += Ra[(w * 16 + trow) * 17 + tcol];
            vs += Rs[(w * 16 + trow) * 17 + tcol];
        }
        const int row = mb + trow, col = nb + tcol;
        if constexpr (MODE == 0) {
            float mu = vm + ba[col];
            float lv = softplusf_(vs + bb[col]);
            float e  = p.eps_q[(long)row * CW * CZ + (long)t * CZ + col];
            float z  = mu + expf(0.5f * lv) * e;
            p.out_mu[(long)row * CW * CZ + (long)t * CZ + col] = mu;
            p.out_lv[(long)row * CW * CZ + (long)t * CZ + col] = lv;
            sta4(p.ztmp_f + (long)row * CZ + col, __float_as_uint(z));
        } else {
            float m  = vm + ba[col];
            float sg = softplusf_(vs + bb[col]);
            float e  = p.eps_p[(long)row * CW * COUT + (long)t * COUT + col];
            p.out_o[(long)row * CW * COUT + (long)t * COUT + col] = m + sg * e;
        }
    }
}

// ---------------------------------------------------------------------------
// Planar flows + LGSSM linear (Q half): r7 structure, 2 rows/WG, 512 threads.
// ---------------------------------------------------------------------------
DEV void phase_flows2(const Prm& p, int wgl, int tid, int t, float* zl, float* ps)
{
    const int rg = tid >> 8;
    const int sub = tid & 255;
    const int c = sub & 127, half = sub >> 7;
    const int row = wgl * 2 + rg;
    float* zrow = zl + rg * CZ;
    float* pall = ps + rg * 2 * CZ;

    if (half == 0)
        zrow[c] = __uint_as_float(lda4(p.ztmp_f + (long)row * CZ + c));
    __syncthreads();

#pragma unroll 1
    for (int kf = 0; kf < 3; ++kf) {
        const float* wr = p.Wp + ((long)kf * CZ + c) * CZ + half * 64;
        const float* zh = zrow + half * 64;
        float s = 0.f;
#pragma unroll
        for (int j = 0; j < 64; j += 4) {
            float4 w = *reinterpret_cast<const float4*>(wr + j);
            s += zh[j] * w.x + zh[j + 1] * w.y + zh[j + 2] * w.z + zh[j + 3] * w.w;
        }
        pall[half * CZ + c] = s;
        __syncthreads();
        if (half == 0) {
            float sf = pall[c] + pall[CZ + c] + p.bp[kf * CZ + c];
            zrow[c] += p.up[kf] * tanhf(sf);
        }
        __syncthreads();
    }
    {
        const float* wr = p.Wlg + (long)c * CZ + half * 64;
        const float* zh = zrow + half * 64;
        float s = 0.f;
#pragma unroll
        for (int j = 0; j < 64; j += 4) {
            float4 w = *reinterpret_cast<const float4*>(wr + j);
            s += zh[j] * w.x + zh[j + 1] * w.y + zh[j + 2] * w.z + zh[j + 3] * w.w;
        }
        pall[half * CZ + c] = s;
        __syncthreads();
        if (half == 0) {
            float zt = pall[c] + pall[CZ + c] + p.blg[c];
            float ztB = __shfl_xor(zt, 1);
            if (!(c & 1)) {
                sta4(p.ztlg  + ((size_t)t * CB + row) * CZ + c, pk2(zt, ztB));
                sta4(p.zflow + ((size_t)(t + 1) * CB + row) * CZ + c,
                     pk2(zrow[c], zrow[c + 1]));
            }
        }
    }
}

// ---------------------------------------------------------------------------
// Mega kernel: 512 threads, 8 waves. M-major tiling: r0 = (wgl>>3)*16 rows,
// n0 = (wgl&7)*128 cols (XCD-aligned weight slices).
// ---------------------------------------------------------------------------
__launch_bounds__(512)
__global__ void mega(Prm p)
{
    extern __shared__ char smem[];
    bf16*  abuf = (bf16*)smem;
    float* Ra   = (float*)(smem + ABUF_BYTES);
    float* Rs   = Ra + REDN;
    float* ZLp  = (float*)(smem + ABUF_BYTES + RED2_BYTES);
    float* PSp  = ZLp + 2 * CZ;

    const int wg = blockIdx.x, tid = threadIdx.x;
    const int lane = tid & 63, wave = tid >> 6;
    const bool isQ = wg < 128;
    const int wgl = isQ ? wg : wg - 128;
    const int r0 = (wgl >> 3) * 16;
    const int n0 = (wgl & 7) * 128;

    if (isQ) {
        u32 bk = 0;
#pragma unroll 1
        for (int t = 0; t < CW; ++t) {
            const int bi = t & 1;
            const bf16*  eb_i = bi ? p.e_b1 : p.e_b0;
            const float* ef_i = bi ? p.e_f1 : p.e_f0;
            bf16*  eb_o = bi ? p.e_b0 : p.e_b1;
            float* ef_o = bi ? p.e_f0 : p.e_f1;

            // Q1: GRU encoder (stage [x | e] -> LDS, compute)
            stage_act(abuf, tid, r0, p.x_b + (long)t * CIN, (long)CW * CIN, CIN, 0,
                      eb_i, CH);
            gru_compute(p, abuf, r0, n0, lane, wave, p.Wih_qb, p.Whh_qb,
                        p.bih_q, p.bhh_q, ef_i, ef_o, eb_o);
            gbar_h(p.barQ, wgl, ++bk);
            // Q2: d = [z_prev | e] @ Wd_q^T + bd_q
            stage_act(abuf, tid, r0, p.zflow + (size_t)t * CB * CZ, CZ, CZ, 1,
                      eb_o, CH);
            lin_compute(abuf, r0, n0, lane, wave, CZ + CH, p.Wd_qb, p.bd_q, p.dvec_b);
            gbar_h(p.barQ, wgl, ++bk);
            // Q3: mu / lv / reparam z
            phase_tail2<0>(p, t, wgl, tid, lane, wave, Ra, Rs,
                           p.dvec_b, p.Wmu_qb, p.Wsg_qb, p.bmu_q, p.bsig_q);
            gbar_h(p.barQ, wgl, ++bk);
            // Q4: planar flows + LGSSM linear
            phase_flows2(p, wgl, tid, t, ZLp, PSp);
            // publish z availability
            asm volatile("s_waitcnt vmcnt(0)" ::: "memory");
            __syncthreads();
            if (tid == 0)
                __hip_atomic_store(&p.zbar[wgl], (u32)(t + 1),
                                   __ATOMIC_RELAXED, __HIP_MEMORY_SCOPE_AGENT);
            __syncthreads();
        }
    } else {
        u32 bk = 0;
#pragma unroll 1
        for (int t = 0; t < CW; ++t) {
            if (tid < 128) {
                while (__hip_atomic_load(&p.zbar[tid], __ATOMIC_RELAXED,
                                         __HIP_MEMORY_SCOPE_AGENT) < (u32)(t + 1))
                    __builtin_amdgcn_s_sleep(2);
            }
            __syncthreads();

            const int bi = t & 1;
            const bf16*  db_i = bi ? p.d_b1 : p.d_b0;
            const float* df_i = bi ? p.d_f1 : p.d_f0;
            bf16*  db_o = bi ? p.d_b0 : p.d_b1;
            float* df_o = bi ? p.d_f0 : p.d_f1;

            // P1: GRU decoder (stage [zt | d] -> LDS, compute)
            stage_act(abuf, tid, r0, p.ztlg + (size_t)t * CB * CZ, CZ, CZ, 1,
                      db_i, CH);
            gru_compute(p, abuf, r0, n0, lane, wave, p.Wih_pb, p.Whh_pb,
                        p.bih_p, p.bhh_p, df_i, df_o, db_o);
            gbar_h(p.barP, wgl, ++bk);
            // P2: dd = d @ Wd_p^T + bd_p
            stage_act(abuf, tid, r0, nullptr, 0, 0, 0, db_o, CH);
            lin_compute(abuf, r0, n0, lane, wave, CH, p.Wd_pb, p.bd_p, p.ddvec_b);
            gbar_h(p.barP, wgl, ++bk);
            // P3: output head
            phase_tail2<1>(p, t, wgl, tid, lane, wave, Ra, Rs,
                           p.ddvec_b, p.Wmu_pb, p.Wsg_pb, p.bmu_p, p.bsig_p);
            // ddvec reuse protected by next barP (after GRU t+1)
        }
    }
}

// ---------------------------------------------------------------------------
// Host driver
// ---------------------------------------------------------------------------
extern "C" void kernel_launch(void* const* d_in, const int* in_sizes, int n_in,
                              void* d_out, int out_size, void* d_ws, size_t ws_size,
                              hipStream_t stream)
{
    Prm p;
    const float* x      = (const float*)d_in[0];
    p.eps_q  = (const float*)d_in[1];
    p.eps_p  = (const float*)d_in[2];
    const float* Wih_q  = (const float*)d_in[3];
    const float* Whh_q  = (const float*)d_in[4];
    p.bih_q  = (const float*)d_in[5];
    p.bhh_q  = (const float*)d_in[6];
    const float* Wd_q   = (const float*)d_in[7];
    p.bd_q   = (const float*)d_in[8];
    const float* Wmu_q  = (const float*)d_in[9];
    p.bmu_q  = (const float*)d_in[10];
    const float* Wsig_q = (const float*)d_in[11];
    p.bsig_q = (const float*)d_in[12];
    p.Wp     = (const float*)d_in[13];
    p.bp     = (const float*)d_in[14];
    p.up     = (const float*)d_in[15];
    p.Wlg    = (const float*)d_in[16];
    p.blg    = (const float*)d_in[17];
    const float* Wih_p  = (const float*)d_in[18];
    const float* Whh_p  = (const float*)d_in[19];
    p.bih_p  = (const float*)d_in[20];
    p.bhh_p  = (const float*)d_in[21];
    const float* Wd_p   = (const float*)d_in[22];
    p.bd_p   = (const float*)d_in[23];
    const float* Wmu_p  = (const float*)d_in[24];
    p.bmu_p  = (const float*)d_in[25];
    const float* Wsig_p = (const float*)d_in[26];
    p.bsig_p = (const float*)d_in[27];

    p.out_o  = (float*)d_out;
    p.out_mu = p.out_o + (size_t)CB * CW * COUT;
    p.out_lv = p.out_mu + (size_t)CB * CW * CZ;

    char* wp_ = (char*)d_ws;
    auto carve = [&](size_t bytes) -> void* {
        void* q = (void*)wp_;
        wp_ += (bytes + 255) & ~(size_t)255;
        return q;
    };
    p.e_f0 = (float*)carve((size_t)CB * CH * 4);
    p.e_f1 = (float*)carve((size_t)CB * CH * 4);
    p.e_b0 = (bf16*)carve((size_t)CB * CH * 2);
    p.e_b1 = (bf16*)carve((size_t)CB * CH * 2);
    p.d_f0 = (float*)carve((size_t)CB * CH * 4);
    p.d_f1 = (float*)carve((size_t)CB * CH * 4);
    p.d_b0 = (bf16*)carve((size_t)CB * CH * 2);
    p.d_b1 = (bf16*)carve((size_t)CB * CH * 2);
    p.ztmp_f  = (float*)carve((size_t)CB * CZ * 4);
    p.dvec_b  = (bf16*)carve((size_t)CB * CD * 2);
    p.ddvec_b = (bf16*)carve((size_t)CB * CD * 2);
    p.zflow   = (bf16*)carve((size_t)(CW + 1) * CB * CZ * 2);
    p.ztlg    = (bf16*)carve((size_t)CW * CB * CZ * 2);
    p.barQ    = (u32*)carve(512);
    p.barP    = (u32*)carve(512);
    p.zbar    = (u32*)carve(512);
    bf16* x_b    = (bf16*)carve((size_t)CB * CW * CIN * 2);
    bf16* Wih_qb = (bf16*)carve((size_t)3 * CH * CIN * 2);
    bf16* Whh_qb = (bf16*)carve((size_t)3 * CH * CH * 2);
    bf16* Wd_qb  = (bf16*)carve((size_t)CD * (CZ + CH) * 2);
    bf16* Wmu_qb = (bf16*)carve((size_t)CZ * CD * 2);
    bf16* Wsg_qb = (bf16*)carve((size_t)CZ * CD * 2);
    bf16* Wih_pb = (bf16*)carve((size_t)3 * CH * CZ * 2);
    bf16* Whh_pb = (bf16*)carve((size_t)3 * CH * CH * 2);
    bf16* Wd_pb  = (bf16*)carve((size_t)CD * CH * 2);
    bf16* Wmu_pb = (bf16*)carve((size_t)COUT * CD * 2);
    bf16* Wsg_pb = (bf16*)carve((size_t)COUT * CD * 2);
    p.x_b = x_b;       p.Wih_qb = Wih_qb; p.Whh_qb = Whh_qb;
    p.Wd_qb = Wd_qb;   p.Wmu_qb = Wmu_qb; p.Wsg_qb = Wsg_qb;
    p.Wih_pb = Wih_pb; p.Whh_pb = Whh_pb; p.Wd_pb = Wd_pb;
    p.Wmu_pb = Wmu_pb; p.Wsg_pb = Wsg_pb;

    hipMemsetAsync(p.e_f0, 0, (size_t)CB * CH * 4, stream);
    hipMemsetAsync(p.e_b0, 0, (size_t)CB * CH * 2, stream);
    hipMemsetAsync(p.d_f0, 0, (size_t)CB * CH * 4, stream);
    hipMemsetAsync(p.d_b0, 0, (size_t)CB * CH * 2, stream);
    hipMemsetAsync(p.zflow, 0, (size_t)CB * CZ * 2, stream);   // slot 0 = zeros
    hipMemsetAsync(p.barQ, 0, 512, stream);
    hipMemsetAsync(p.barP, 0, 512, stream);
    hipMemsetAsync(p.zbar, 0, 512, stream);

    auto cvt = [&](const float* s, bf16* d, size_t n) {
        k_cvt<<<dim3((unsigned)((n / 4 + 255) / 256)), dim3(256), 0, stream>>>(s, d, (int)n);
    };
    cvt(x,      x_b,    (size_t)CB * CW * CIN);
    cvt(Wih_q,  Wih_qb, (size_t)3 * CH * CIN);
    cvt(Whh_q,  Whh_qb, (size_t)3 * CH * CH);
    cvt(Wd_q,   Wd_qb,  (size_t)CD * (CZ + CH));
    cvt(Wmu_q,  Wmu_qb, (size_t)CZ * CD);
    cvt(Wsig_q, Wsg_qb, (size_t)CZ * CD);
    cvt(Wih_p,  Wih_pb, (size_t)3 * CH * CZ);
    cvt(Whh_p,  Whh_pb, (size_t)3 * CH * CH);
    cvt(Wd_p,   Wd_pb,  (size_t)CD * CH);
    cvt(Wmu_p,  Wmu_pb, (size_t)COUT * CD);
    cvt(Wsig_p, Wsg_pb, (size_t)COUT * CD);

    mega<<<dim3(256), dim3(512), SMEM_BYTES, stream>>>(p);
}